// Round 17
// baseline (5293.567 us; speedup 1.0000x reference)
//
#include <hip/hip_runtime.h>
#include <stdint.h>

#define DEVFN __device__ __forceinline__
#define SCOPE_AGENT __HIP_MEMORY_SCOPE_AGENT

static constexpr int B_ = 16;
static constexpr int S_ = 1024;
static constexpr int FR = 128;     // FULL_RANGE
static constexpr int MU = 32;      // MOOD_UNITS
static constexpr int H_ = 512;     // UNITS
static constexpr int G4 = 2048;    // 4*H

// packed-weight chunk counts (16B chunks of 8 f16 weights)
static constexpr int NCH_WHH = 4 * 64 * 2048;              // 524288
static constexpr int NCH_WI0 = 16 * 2048;                  // 32768
static constexpr int NCH_WIR = 3 * 64 * 2048;              // 393216
static constexpr int NCH_TOT = NCH_WHH + NCH_WI0 + NCH_WIR;

static constexpr int HV64 = 128 * 256;    // u64 tagged h-slots per phase (per layer region)
static constexpr int NXF = 16 * 16 * 16;  // x-flags per pair: 16 groups x 16 producers, 64B pad

typedef _Float16 h2_t __attribute__((ext_vector_type(2)));

DEVFN uint16_t f2h(float x) { union { _Float16 f; uint16_t u; } c; c.f = (_Float16)x; return c.u; }
DEVFN uint32_t pack_f16(float a, float b) { return (uint32_t)f2h(a) | ((uint32_t)f2h(b) << 16); }

DEVFN float fd2(uint32_t a, uint32_t b, float c) {
#if __has_builtin(__builtin_amdgcn_fdot2)
    return __builtin_amdgcn_fdot2(__builtin_bit_cast(h2_t, a),
                                  __builtin_bit_cast(h2_t, b), c, false);
#else
    asm("v_dot2_f32_f16 %0, %1, %2, %0" : "+v"(c) : "v"(a), "v"(b));
    return c;
#endif
}
// 8 f16 weights . 8 f16 inputs (both as uint4), f32 accumulate
DEVFN float dot8f(uint4 w, uint4 x, float s) {
    s = fd2(w.x, x.x, s); s = fd2(w.y, x.y, s);
    s = fd2(w.z, x.z, s); s = fd2(w.w, x.w, s);
    return s;
}
DEVFN float sigm(float x) { return 1.0f / (1.0f + __expf(-x)); }
DEVFN float tanhfast(float x) {
    float e = __expf(2.0f * fabsf(x));
    float r = 1.0f - 2.0f / (e + 1.0f);   // e==inf -> r=1
    return copysignf(r, x);
}

// ---------------------------------------------------------------------------
// mood: m = moods@W_mood.T + b_mood ; mc[b][row] = m@Wih0[:,128:160].T + bih0 + bhh0
// ---------------------------------------------------------------------------
__global__ __launch_bounds__(256) void mood_kernel(
    const float* __restrict__ moods, const float* __restrict__ W_mood,
    const float* __restrict__ b_mood, const float* __restrict__ W_ih0,
    const float* __restrict__ b_ih0, const float* __restrict__ b_hh0,
    float* __restrict__ mc)
{
    int b = blockIdx.x, tid = threadIdx.x;
    __shared__ float m[MU];
    if (tid < MU) {
        float s = b_mood[tid];
        #pragma unroll
        for (int j = 0; j < 4; j++) s += moods[b * 4 + j] * W_mood[tid * 4 + j];
        m[tid] = s;
    }
    __syncthreads();
    for (int row = tid; row < G4; row += 256) {
        float s = b_ih0[row] + b_hh0[row];
        const float* w = W_ih0 + (size_t)row * (FR + MU) + FR;
        #pragma unroll
        for (int u = 0; u < MU; u++) s += m[u] * w[u];
        mc[(size_t)b * G4 + row] = s;
    }
}

// ---------------------------------------------------------------------------
// Pre-pack weights to f16 chunks (16B = 8 weights), one thread per chunk.
// ---------------------------------------------------------------------------
__global__ __launch_bounds__(256) void pack_kernel(
    const float* __restrict__ W_hh0, const float* __restrict__ W_hh_r,
    const float* __restrict__ W_ih0, const float* __restrict__ W_ih_r,
    uint4* __restrict__ pwh, uint4* __restrict__ pwi0, uint4* __restrict__ pwir)
{
    int c = blockIdx.x * 256 + threadIdx.x;
    if (c >= NCH_TOT) return;
    const float* src;
    uint4* dst;
    if (c < NCH_WHH) {
        int l = c >> 17, ck = (c >> 11) & 63, row = c & 2047;
        const float* W = (l == 0) ? W_hh0 : W_hh_r + (size_t)(l - 1) * G4 * H_;
        src = W + (size_t)row * H_ + ck * 8;
        dst = pwh + c;
    } else if (c < NCH_WHH + NCH_WI0) {
        int d = c - NCH_WHH;
        int ck = d >> 11, row = d & 2047;
        src = W_ih0 + (size_t)row * (FR + MU) + ck * 8;
        dst = pwi0 + d;
    } else {
        int e = c - NCH_WHH - NCH_WI0;
        int l = e >> 17, ck = (e >> 11) & 63, row = e & 2047;
        src = W_ih_r + (size_t)l * G4 * H_ + (size_t)row * H_ + ck * 8;
        dst = pwir + e;
    }
    uint4 o;
    o.x = pack_f16(src[0], src[1]);
    o.y = pack_f16(src[2], src[3]);
    o.z = pack_f16(src[4], src[5]);
    o.w = pack_f16(src[6], src[7]);
    *dst = o;
}

// register-resident Whh chunk J applied to all SB sub-batches (WREG layers)
#define HSTEP(J) { \
    _Pragma("unroll") \
    for (int b = 0; b < SB; b++) { \
        uint4 hv = *(const uint4*)&lds_h[b * H_ + kg * 64 + (J) * 8]; \
        accA[b] = dot8f(h0c##J, hv, accA[b]); \
        accB[b] = dot8f(h1c##J, hv, accB[b]); \
    } }

// x-part j-iteration body (Wih stream)
#define XBODY(J) { \
    uint4 w0 = WI0[(size_t)(J) * G4 + row0]; \
    uint4 w1 = WI0[(size_t)(J) * G4 + row1]; \
    _Pragma("unroll") \
    for (int b = 0; b < SB; b++) { \
        uint4 xv = *(const uint4*)&lds_x[b * KIN + kg * (KIN / 8) + (J) * 8]; \
        accA[b] = dot8f(w0, xv, accA[b]); \
        accB[b] = dot8f(w1, xv, accB[b]); \
    } }

// ---------------------------------------------------------------------------
// Pipelined dilated-LSTM scan body (one layer role inside a fused kernel).
// Fused pairs (L0||L1, L2||L3), 2 WGs/CU co-resident (waves_per_eu(4,4),
// LDS<=51KB -> strict 2/CU capacity -> all 512 WGs resident -> deadlock-free;
// deps flow only producer->consumer). Consumer gated by monotonic x-flags;
// producer x stores agent-atomic, certified after vmcnt drain. h exchange:
// per-layer tagged 8B slots. In-place safety: prefetch drains before h-tag
// publish; writers gated on those tags. Residual read right after (a) (R15
// race fix: lds_res stable in [(a) of t, staging of t+1)).
// ---------------------------------------------------------------------------
template <int LAYER>
DEVFN void scan_body(
    int bid, const float* x_in, float* x_out,
    const uint4* __restrict__ pwi, const uint4* __restrict__ pwh,
    const float* __restrict__ biasA, const float* __restrict__ biasB,
    unsigned long long* __restrict__ hb64, uint32_t* __restrict__ xf,
    uint16_t* lds_x, uint16_t* lds_h, float* lds_p, float* lds_res)
{
    constexpr int DIL = 1 << LAYER;
    constexpr int SB = DIL;
    constexpr int T = S_ / DIL;
    constexpr int KIN = (LAYER == 0) ? FR : H_;
    constexpr int NJX = KIN / 64;
    constexpr int XTOT = SB * KIN;
    constexpr int XRS = (XTOT + 511) / 512;
    constexpr int KSH = (LAYER == 0) ? 7 : 9;
    constexpr int LOFF = (LAYER == 0) ? 0 : (LAYER - 1);
    constexpr bool WREG = (LAYER <= 1);      // Whh register residency
    constexpr bool EARLY = (SB <= 4);        // early h-poll issue
    constexpr bool XPROD = (LAYER == 0 || LAYER == 2);  // atomic x_out + flags
    constexpr bool XCONS = (LAYER == 1 || LAYER == 3);  // gated atomic x_in
    constexpr uint32_t TB = 1u;              // tag base (per-layer region)

    const int g = bid & 15, wgi = bid >> 4;
    const int tid = threadIdx.x;
    const int kg = tid >> 6;
    const int r6 = tid & 63;
    const int gp = r6 >> 5;
    const int um = r6 & 31;
    const int U0 = wgi * 32;
    const int row0 = (2 * gp) * H_ + U0 + um;
    const int row1 = row0 + H_;
    const int rl0 = (2 * gp) * 32 + um, rl1 = rl0 + 32;
    const int sb0 = g * SB;

    const uint4* WH = pwh + ((size_t)(LAYER * 64 + kg * 8)) * G4;

    uint4 h0c0, h1c0, h0c1, h1c1, h0c2, h1c2, h0c3, h1c3;
    uint4 h0c4, h1c4, h0c5, h1c5, h0c6, h1c6, h0c7, h1c7;
    if constexpr (WREG) {
        h0c0 = WH[(size_t)0 * G4 + row0]; h1c0 = WH[(size_t)0 * G4 + row1];
        h0c1 = WH[(size_t)1 * G4 + row0]; h1c1 = WH[(size_t)1 * G4 + row1];
        h0c2 = WH[(size_t)2 * G4 + row0]; h1c2 = WH[(size_t)2 * G4 + row1];
        h0c3 = WH[(size_t)3 * G4 + row0]; h1c3 = WH[(size_t)3 * G4 + row1];
        h0c4 = WH[(size_t)4 * G4 + row0]; h1c4 = WH[(size_t)4 * G4 + row1];
        h0c5 = WH[(size_t)5 * G4 + row0]; h1c5 = WH[(size_t)5 * G4 + row1];
        h0c6 = WH[(size_t)6 * G4 + row0]; h1c6 = WH[(size_t)6 * G4 + row1];
        h0c7 = WH[(size_t)7 * G4 + row0]; h1c7 = WH[(size_t)7 * G4 + row1];
    }

    const uint4* WI0;
    if constexpr (LAYER == 0) WI0 = pwi + ((size_t)(kg * NJX)) * G4;
    else                      WI0 = pwi + ((size_t)(LOFF * 64 + kg * 8)) * G4;

    const int b0 = tid >> 5, uu = tid & 31;
    const bool upd = tid < SB * 32;
    float biasv[4] = {0.f, 0.f, 0.f, 0.f};
    float cst = 0.0f;
    if (upd) {
        #pragma unroll
        for (int Gx = 0; Gx < 4; Gx++) {
            int RR = Gx * H_ + U0 + uu;
            if constexpr (LAYER == 0)
                biasv[Gx] = biasA[(size_t)(sb0 + b0) * G4 + RR];
            else
                biasv[Gx] = biasA[RR] + biasB[RR];
        }
    }
    const size_t pslot = (size_t)(sb0 + b0) * 256 + ((U0 + uu) >> 1);
    const int usb = sb0 + b0, ubg = usb >> LAYER, uk = usb & (DIL - 1);
    const int myprod = (tid & 511) >> 5;   // producer WG of this thread's units

    // ---- prologue ----
    if constexpr (XCONS) {   // gate token-0 prefetch: positions < DIL -> flag >= 2
        const uint32_t* fl = xf + (g * 16 + myprod) * 16;
        uint32_t fv = __hip_atomic_load(fl, __ATOMIC_RELAXED, SCOPE_AGENT);
        while (fv < 2u) {
            __builtin_amdgcn_s_sleep(1);
            fv = __hip_atomic_load(fl, __ATOMIC_RELAXED, SCOPE_AGENT);
        }
    }
    float xsr[XRS];
    #pragma unroll
    for (int rr = 0; rr < XRS; rr++) {
        int idx = tid + rr * 512;
        if (idx < XTOT) {
            int b = idx >> KSH, off = idx & (KIN - 1);
            int sb = sb0 + b, bg = sb >> LAYER, k = sb & (DIL - 1);
            const float* src = x_in + ((size_t)bg * S_ + k) * KIN + off;
            if constexpr (XCONS)
                xsr[rr] = __hip_atomic_load(src, __ATOMIC_RELAXED, SCOPE_AGENT);
            else
                xsr[rr] = *src;
        }
    }
    asm volatile("s_waitcnt vmcnt(0)" ::: "memory");
    __syncthreads();
    if (upd && ((uu & 1) == 0))
        __hip_atomic_store(hb64 + HV64 + pslot,
                           (unsigned long long)TB << 32,
                           __ATOMIC_RELAXED, SCOPE_AGENT);

    for (int t = 0; t < T; t++) {
        // ---- stage regs -> LDS (f16) + f32 residual slice ----
        #pragma unroll
        for (int rr = 0; rr < XRS; rr++) {
            int idx = tid + rr * 512;
            if (idx < XTOT) {
                int b = idx >> KSH, off = idx & (KIN - 1);
                lds_x[b * KIN + off] = f2h(xsr[rr]);
                if constexpr (LAYER > 0)
                    if ((off & ~31) == U0) lds_res[b * 32 + (off & 31)] = xsr[rr];
            }
        }
        __syncthreads();   // (a)

        // ---- residual -> register NOW (R15 race fix) ----
        float res = 0.f;
        if constexpr (LAYER > 0) {
            if (upd) res = lds_res[b0 * 32 + uu];
        }

        const unsigned long long* hrd = hb64 + (size_t)((t + 1) & 1) * HV64;
        const uint32_t want = TB + (uint32_t)t;

        // ---- early h-poll issue ----
        unsigned long long pve[EARLY ? SB : 1];
        if constexpr (EARLY) {
            if (tid < 256) {
                #pragma unroll
                for (int b = 0; b < SB; b++)
                    pve[b] = __hip_atomic_load(hrd + (size_t)(sb0 + b) * 256 + tid,
                                               __ATOMIC_RELAXED, SCOPE_AGENT);
            }
        }

        // ---- x-flag gate + token(t+1) prefetch ----
        if (t + 1 < T) {
            if constexpr (XCONS) {
                const uint32_t* fl = xf + (g * 16 + myprod) * 16;
                const uint32_t need = 2u * (uint32_t)(t + 2);
                uint32_t fv = __hip_atomic_load(fl, __ATOMIC_RELAXED, SCOPE_AGENT);
                while (fv < need) {
                    __builtin_amdgcn_s_sleep(1);
                    fv = __hip_atomic_load(fl, __ATOMIC_RELAXED, SCOPE_AGENT);
                }
            }
            #pragma unroll
            for (int rr = 0; rr < XRS; rr++) {
                int idx = tid + rr * 512;
                if (idx < XTOT) {
                    int b = idx >> KSH, off = idx & (KIN - 1);
                    int sb = sb0 + b, bg = sb >> LAYER, k = sb & (DIL - 1);
                    const float* src =
                        x_in + ((size_t)bg * S_ + (size_t)(t + 1) * DIL + k) * KIN + off;
                    if constexpr (XCONS)
                        xsr[rr] = __hip_atomic_load(src, __ATOMIC_RELAXED, SCOPE_AGENT);
                    else
                        xsr[rr] = *src;
                }
            }
        }

        // ---- x-part matvec ----
        float accA[SB], accB[SB];
        #pragma unroll
        for (int b = 0; b < SB; b++) { accA[b] = 0.f; accB[b] = 0.f; }
        if constexpr (LAYER >= 2) {
            #pragma unroll 4
            for (int j = 0; j < NJX; j++) XBODY(j)
        } else {
            #pragma unroll 2
            for (int j = 0; j < NJX; j++) XBODY(j)
        }

        // ---- drain prefetch/polls before spin (retries wait only on selves;
        //      also the in-place certificate: prefetch landed before publish) ----
        asm volatile("s_waitcnt vmcnt(0)" ::: "memory");

        // ---- h tag spin + h -> LDS ----
        if (tid < 256) {
            if constexpr (EARLY) {
                #pragma unroll
                for (int b = 0; b < SB; b++) {
                    unsigned long long v = pve[b];
                    while ((uint32_t)(v >> 32) != want) {
                        __builtin_amdgcn_s_sleep(1);
                        v = __hip_atomic_load(hrd + (size_t)(sb0 + b) * 256 + tid,
                                              __ATOMIC_RELAXED, SCOPE_AGENT);
                    }
                    ((uint32_t*)&lds_h[b * H_])[tid] = (uint32_t)v;
                }
            } else {
                unsigned long long pv[SB];
                #pragma unroll
                for (int b = 0; b < SB; b++)
                    pv[b] = __hip_atomic_load(hrd + (size_t)(sb0 + b) * 256 + tid,
                                              __ATOMIC_RELAXED, SCOPE_AGENT);
                #pragma unroll
                for (int b = 0; b < SB; b++) {
                    while ((uint32_t)(pv[b] >> 32) != want) {
                        __builtin_amdgcn_s_sleep(1);
                        pv[b] = __hip_atomic_load(hrd + (size_t)(sb0 + b) * 256 + tid,
                                                  __ATOMIC_RELAXED, SCOPE_AGENT);
                    }
                    ((uint32_t*)&lds_h[b * H_])[tid] = (uint32_t)pv[b];
                }
            }
        }
        __syncthreads();   // (b)

        // ---- recurrent matvec ----
        if constexpr (WREG) {
            HSTEP(0) HSTEP(1) HSTEP(2) HSTEP(3)
            HSTEP(4) HSTEP(5) HSTEP(6) HSTEP(7)
        } else {
            #pragma unroll 4
            for (int j = 0; j < 8; j++) {
                uint4 w0 = WH[(size_t)j * G4 + row0];
                uint4 w1 = WH[(size_t)j * G4 + row1];
                #pragma unroll
                for (int b = 0; b < SB; b++) {
                    uint4 hv = *(const uint4*)&lds_h[b * H_ + kg * 64 + j * 8];
                    accA[b] = dot8f(w0, hv, accA[b]);
                    accB[b] = dot8f(w1, hv, accB[b]);
                }
            }
        }

        // ---- partials; barrier (c) ----
        #pragma unroll
        for (int b = 0; b < SB; b++) {
            lds_p[(b * 8 + kg) * 132 + rl0] = accA[b];
            lds_p[(b * 8 + kg) * 132 + rl1] = accB[b];
        }
        asm volatile("s_waitcnt vmcnt(0)" ::: "memory");
        __syncthreads();   // (c)

        // ---- gates; tagged h publish; x_out; x-flag certify ----
        if (upd) {
            float gv[4];
            #pragma unroll
            for (int Gx = 0; Gx < 4; Gx++) {
                int rl = Gx * 32 + uu;
                float s = biasv[Gx];
                #pragma unroll
                for (int q = 0; q < 8; q++) s += lds_p[(b0 * 8 + q) * 132 + rl];
                gv[Gx] = s;
            }
            float ci = sigm(gv[0]), cf = sigm(gv[1]);
            float cg = tanhfast(gv[2]), co = sigm(gv[3]);
            cst = cf * cst + ci * cg;
            float hv = co * tanhfast(cst);
            uint32_t h16 = (uint32_t)f2h(hv);
            uint32_t partner = (uint32_t)__shfl_xor((int)h16, 1);
            if ((uu & 1) == 0)
                __hip_atomic_store(hb64 + (size_t)(t & 1) * HV64 + pslot,
                                   ((unsigned long long)(TB + (uint32_t)t + 1) << 32) |
                                   (unsigned long long)(h16 | (partner << 16)),
                                   __ATOMIC_RELAXED, SCOPE_AGENT);
            float* dst = x_out + ((size_t)ubg * S_ + (size_t)t * DIL + uk) * H_ + U0 + uu;
            if constexpr (XPROD)
                __hip_atomic_store(dst, hv + res, __ATOMIC_RELAXED, SCOPE_AGENT);
            else
                *dst = hv + res;
        }
        if constexpr (XPROD) {
            asm volatile("s_waitcnt vmcnt(0)" ::: "memory");
            if constexpr (SB >= 4) __syncthreads();   // L2: cross-wave upd stores
            if (tid == 0)
                __hip_atomic_store(xf + (g * 16 + wgi) * 16, (uint32_t)(t + 1),
                                   __ATOMIC_RELAXED, SCOPE_AGENT);
        }
    }
}

// ---------------------------------------------------------------------------
// Fused pair kernel with XCD-SEGREGATED layer mapping (R16 fix).
// R16 counters: K2 was HBM-bound (6.3GB FETCH @2.47TB/s) because bid%8
// round-robin put BOTH layers on every XCD -> 8MB/step weight working set
// through a 4MB L2 -> thrash. NEW: layer A on XCDs 0-3, layer B on XCDs 4-7
// (per-XCD working set = one 4MB layer slice; cross-step L2 reuse returns).
// All 16 WGs of a group stay on one XCD (h-exchange L2-local). Mapping is
// perf-only: co-residency comes from strict 2-WG/CU capacity, not placement.
// ---------------------------------------------------------------------------
template <int LA, int LB>
__global__ __attribute__((amdgpu_waves_per_eu(4, 4))) __launch_bounds__(512)
void fused_scan(const float* xinA, float* xoutA,
                const float* xinB, float* xoutB,
                const uint4* __restrict__ pwiA, const uint4* __restrict__ pwiB,
                const uint4* __restrict__ pwh,
                const float* __restrict__ bA1, const float* __restrict__ bA2,
                const float* __restrict__ bB1, const float* __restrict__ bB2,
                unsigned long long* __restrict__ hb64, uint32_t* __restrict__ xf)
{
    constexpr int SBMX = 1 << LB;
    __shared__ __align__(16) uint16_t s_x[SBMX * 512];
    __shared__ __align__(16) uint16_t s_h[SBMX * 512];
    __shared__ float s_p[SBMX * 8 * 132];
    __shared__ float s_r[SBMX * 32];
    // XCD = blockIdx.x % 8 under round-robin. x<4 -> layer A, else layer B.
    // bid = wgi*16 + g with g = xe + 4*(q&3), wgi = q>>2  (bijective; group's
    // 16 WGs share one XCD).
    const int x = (int)blockIdx.x & 7, q = (int)blockIdx.x >> 3;
    const bool isA = (x < 4);
    const int xe = isA ? x : x - 4;
    const int bid = ((q >> 2) << 4) + (xe + 4 * (q & 3));
    if (isA)
        scan_body<LA>(bid, xinA, xoutA, pwiA, pwh, bA1, bA2,
                      hb64 + (size_t)LA * 2 * HV64, xf, s_x, s_h, s_p, s_r);
    else
        scan_body<LB>(bid, xinB, xoutB, pwiB, pwh, bB1, bB2,
                      hb64 + (size_t)LB * 2 * HV64, xf, s_x, s_h, s_p, s_r);
}

// ---------------------------------------------------------------------------
// out = x @ W_out.T + b_out   ([16384,512] x [512,128])
// ---------------------------------------------------------------------------
__global__ __launch_bounds__(256) void out_gemm(
    const float* __restrict__ x, const float* __restrict__ Wout,
    const float* __restrict__ bout, float* __restrict__ out)
{
    __shared__ __align__(16) float xs[8][H_];
    int tid = threadIdx.x;
    size_t tok0 = (size_t)blockIdx.x * 8;
    const float4* src = (const float4*)(x + tok0 * H_);
    for (int idx = tid; idx < 8 * H_ / 4; idx += 256)
        ((float4*)xs)[idx] = src[idx];
    __syncthreads();

    int col = tid & 127, th = tid >> 7;
    int tb = th * 4;
    float a0 = 0.f, a1 = 0.f, a2 = 0.f, a3 = 0.f;
    const float4* w = (const float4*)(Wout + (size_t)col * H_);
    #pragma unroll 4
    for (int j = 0; j < H_ / 4; j++) {
        float4 wv = w[j];
        float4 x0 = ((const float4*)xs[tb + 0])[j];
        float4 x1 = ((const float4*)xs[tb + 1])[j];
        float4 x2 = ((const float4*)xs[tb + 2])[j];
        float4 x3 = ((const float4*)xs[tb + 3])[j];
        a0 = fmaf(wv.x, x0.x, a0); a0 = fmaf(wv.y, x0.y, a0); a0 = fmaf(wv.z, x0.z, a0); a0 = fmaf(wv.w, x0.w, a0);
        a1 = fmaf(wv.x, x1.x, a1); a1 = fmaf(wv.y, x1.y, a1); a1 = fmaf(wv.z, x1.z, a1); a1 = fmaf(wv.w, x1.w, a1);
        a2 = fmaf(wv.x, x2.x, a2); a2 = fmaf(wv.y, x2.y, a2); a2 = fmaf(wv.z, x2.z, a2); a2 = fmaf(wv.w, x2.w, a2);
        a3 = fmaf(wv.x, x3.x, a3); a3 = fmaf(wv.y, x3.y, a3); a3 = fmaf(wv.z, x3.z, a3); a3 = fmaf(wv.w, x3.w, a3);
    }
    float bo = bout[col];
    out[(tok0 + tb + 0) * FR + col] = a0 + bo;
    out[(tok0 + tb + 1) * FR + col] = a1 + bo;
    out[(tok0 + tb + 2) * FR + col] = a2 + bo;
    out[(tok0 + tb + 3) * FR + col] = a3 + bo;
}

// ---------------------------------------------------------------------------
extern "C" void kernel_launch(void* const* d_in, const int* in_sizes, int n_in,
                              void* d_out, int out_size, void* d_ws, size_t ws_size,
                              hipStream_t stream)
{
    const float* inputs = (const float*)d_in[0];
    const float* moods  = (const float*)d_in[1];
    const float* W_mood = (const float*)d_in[2];
    const float* b_mood = (const float*)d_in[3];
    const float* W_ih0  = (const float*)d_in[4];
    const float* W_hh0  = (const float*)d_in[5];
    const float* b_ih0  = (const float*)d_in[6];
    const float* b_hh0  = (const float*)d_in[7];
    const float* W_ih_r = (const float*)d_in[8];
    const float* W_hh_r = (const float*)d_in[9];
    const float* b_ih_r = (const float*)d_in[10];
    const float* b_hh_r = (const float*)d_in[11];
    const float* W_out  = (const float*)d_in[12];
    const float* b_out  = (const float*)d_in[13];

    float* ws = (float*)d_ws;
    float* mc = ws;                                    // 32768 floats
    float* xA = ws + 32768;                            // 8388608 floats (in-place x)
    unsigned long long* hb64 = (unsigned long long*)(xA + 8388608);  // 4 layers x 2*HV64 = 2MB
    uint32_t* xf0 = (uint32_t*)(hb64 + 8 * HV64);      // 16KB (L0->L1 flags)
    uint32_t* xf2 = xf0 + NXF;                         // 16KB (L2->L3 flags)
    uint4* pwh  = (uint4*)(xf2 + NXF);                 // 524288 uint4
    uint4* pwi0 = pwh + NCH_WHH;                       // 32768 uint4
    uint4* pwir = pwi0 + NCH_WI0;                      // 393216 uint4
    // total ~51 MB

    // zero all tags + flags each launch (replay-safe)
    (void)hipMemsetAsync(hb64, 0, 8 * HV64 * sizeof(unsigned long long)
                                  + 2 * NXF * sizeof(uint32_t), stream);
    mood_kernel<<<16, 256, 0, stream>>>(moods, W_mood, b_mood, W_ih0, b_ih0, b_hh0, mc);
    pack_kernel<<<(NCH_TOT + 255) / 256, 256, 0, stream>>>(
        W_hh0, W_hh_r, W_ih0, W_ih_r, pwh, pwi0, pwir);

    // K1: L0 (inputs -> xA, atomic+flags) || L1 (xA gated -> xA plain)
    fused_scan<0, 1><<<512, 512, 0, stream>>>(
        inputs, xA, xA, xA, pwi0, pwir, pwh,
        mc, nullptr, b_ih_r, b_hh_r, hb64, xf0);
    // K2: L2 (xA plain-in -> xA atomic+flags) || L3 (xA gated -> xA plain)
    fused_scan<2, 3><<<512, 512, 0, stream>>>(
        xA, xA, xA, xA, pwir, pwir, pwh,
        b_ih_r + G4, b_hh_r + G4, b_ih_r + 2 * G4, b_hh_r + 2 * G4, hb64, xf2);

    out_gemm<<<2048, 256, 0, stream>>>(xA, W_out, b_out, (float*)d_out);
}

// Round 18
// 5047.155 us; speedup vs baseline: 1.0488x; 1.0488x over previous
//
#include <hip/hip_runtime.h>
#include <stdint.h>

#define DEVFN __device__ __forceinline__
#define SCOPE_AGENT __HIP_MEMORY_SCOPE_AGENT

static constexpr int B_ = 16;
static constexpr int S_ = 1024;
static constexpr int FR = 128;     // FULL_RANGE
static constexpr int MU = 32;      // MOOD_UNITS
static constexpr int H_ = 512;     // UNITS
static constexpr int G4 = 2048;    // 4*H

// packed-weight chunk counts (16B chunks of 8 f16 weights)
static constexpr int NCH_WHH = 4 * 64 * 2048;              // 524288
static constexpr int NCH_WI0 = 16 * 2048;                  // 32768
static constexpr int NCH_WIR = 3 * 64 * 2048;              // 393216
static constexpr int NCH_TOT = NCH_WHH + NCH_WI0 + NCH_WIR;

static constexpr int HV64 = 128 * 256;    // u64 tagged h-slots per phase (per layer region)
static constexpr int NXF = 16 * 16 * 16;  // x-flags per pair: 16 groups x 16 producers, 64B pad

typedef _Float16 h2_t __attribute__((ext_vector_type(2)));

DEVFN uint16_t f2h(float x) { union { _Float16 f; uint16_t u; } c; c.f = (_Float16)x; return c.u; }
DEVFN uint32_t pack_f16(float a, float b) { return (uint32_t)f2h(a) | ((uint32_t)f2h(b) << 16); }

DEVFN float fd2(uint32_t a, uint32_t b, float c) {
#if __has_builtin(__builtin_amdgcn_fdot2)
    return __builtin_amdgcn_fdot2(__builtin_bit_cast(h2_t, a),
                                  __builtin_bit_cast(h2_t, b), c, false);
#else
    asm("v_dot2_f32_f16 %0, %1, %2, %0" : "+v"(c) : "v"(a), "v"(b));
    return c;
#endif
}
// 8 f16 weights . 8 f16 inputs (both as uint4), f32 accumulate
DEVFN float dot8f(uint4 w, uint4 x, float s) {
    s = fd2(w.x, x.x, s); s = fd2(w.y, x.y, s);
    s = fd2(w.z, x.z, s); s = fd2(w.w, x.w, s);
    return s;
}
DEVFN float sigm(float x) { return 1.0f / (1.0f + __expf(-x)); }
DEVFN float tanhfast(float x) {
    float e = __expf(2.0f * fabsf(x));
    float r = 1.0f - 2.0f / (e + 1.0f);   // e==inf -> r=1
    return copysignf(r, x);
}

// ---------------------------------------------------------------------------
// mood: m = moods@W_mood.T + b_mood ; mc[b][row] = m@Wih0[:,128:160].T + bih0 + bhh0
// ---------------------------------------------------------------------------
__global__ __launch_bounds__(256) void mood_kernel(
    const float* __restrict__ moods, const float* __restrict__ W_mood,
    const float* __restrict__ b_mood, const float* __restrict__ W_ih0,
    const float* __restrict__ b_ih0, const float* __restrict__ b_hh0,
    float* __restrict__ mc)
{
    int b = blockIdx.x, tid = threadIdx.x;
    __shared__ float m[MU];
    if (tid < MU) {
        float s = b_mood[tid];
        #pragma unroll
        for (int j = 0; j < 4; j++) s += moods[b * 4 + j] * W_mood[tid * 4 + j];
        m[tid] = s;
    }
    __syncthreads();
    for (int row = tid; row < G4; row += 256) {
        float s = b_ih0[row] + b_hh0[row];
        const float* w = W_ih0 + (size_t)row * (FR + MU) + FR;
        #pragma unroll
        for (int u = 0; u < MU; u++) s += m[u] * w[u];
        mc[(size_t)b * G4 + row] = s;
    }
}

// ---------------------------------------------------------------------------
// Pre-pack weights to f16 chunks (16B = 8 weights), one thread per chunk.
// ---------------------------------------------------------------------------
__global__ __launch_bounds__(256) void pack_kernel(
    const float* __restrict__ W_hh0, const float* __restrict__ W_hh_r,
    const float* __restrict__ W_ih0, const float* __restrict__ W_ih_r,
    uint4* __restrict__ pwh, uint4* __restrict__ pwi0, uint4* __restrict__ pwir)
{
    int c = blockIdx.x * 256 + threadIdx.x;
    if (c >= NCH_TOT) return;
    const float* src;
    uint4* dst;
    if (c < NCH_WHH) {
        int l = c >> 17, ck = (c >> 11) & 63, row = c & 2047;
        const float* W = (l == 0) ? W_hh0 : W_hh_r + (size_t)(l - 1) * G4 * H_;
        src = W + (size_t)row * H_ + ck * 8;
        dst = pwh + c;
    } else if (c < NCH_WHH + NCH_WI0) {
        int d = c - NCH_WHH;
        int ck = d >> 11, row = d & 2047;
        src = W_ih0 + (size_t)row * (FR + MU) + ck * 8;
        dst = pwi0 + d;
    } else {
        int e = c - NCH_WHH - NCH_WI0;
        int l = e >> 17, ck = (e >> 11) & 63, row = e & 2047;
        src = W_ih_r + (size_t)l * G4 * H_ + (size_t)row * H_ + ck * 8;
        dst = pwir + e;
    }
    uint4 o;
    o.x = pack_f16(src[0], src[1]);
    o.y = pack_f16(src[2], src[3]);
    o.z = pack_f16(src[4], src[5]);
    o.w = pack_f16(src[6], src[7]);
    *dst = o;
}

// register-resident Whh chunk J applied to all SB sub-batches (WREG layers)
#define HSTEP(J) { \
    _Pragma("unroll") \
    for (int b = 0; b < SB; b++) { \
        uint4 hv = *(const uint4*)&lds_h[b * H_ + kg * 64 + (J) * 8]; \
        accA[b] = dot8f(h0c##J, hv, accA[b]); \
        accB[b] = dot8f(h1c##J, hv, accB[b]); \
    } }

// x-part j-iteration body (Wih stream)
#define XBODY(J) { \
    uint4 w0 = WI0[(size_t)(J) * G4 + row0]; \
    uint4 w1 = WI0[(size_t)(J) * G4 + row1]; \
    _Pragma("unroll") \
    for (int b = 0; b < SB; b++) { \
        uint4 xv = *(const uint4*)&lds_x[b * KIN + kg * (KIN / 8) + (J) * 8]; \
        accA[b] = dot8f(w0, xv, accA[b]); \
        accB[b] = dot8f(w1, xv, accB[b]); \
    } }

// ---------------------------------------------------------------------------
// Pipelined dilated-LSTM scan body (one layer role inside a fused kernel).
// Fused pairs (L0||L1, L2||L3), 2 WGs/CU co-resident (waves_per_eu(4,4),
// LDS<=51KB -> strict 2/CU capacity -> all 512 WGs resident -> deadlock-free;
// deps flow only producer->consumer). Consumer gated by monotonic x-flags;
// producer x stores agent-atomic, certified after vmcnt drain. h exchange:
// per-layer tagged 8B slots. In-place safety: prefetch drains before h-tag
// publish; writers gated on those tags. Residual read right after (a) (R15
// race fix: lds_res stable in [(a) of t, staging of t+1)).
// ---------------------------------------------------------------------------
template <int LAYER>
DEVFN void scan_body(
    int bid, const float* x_in, float* x_out,
    const uint4* __restrict__ pwi, const uint4* __restrict__ pwh,
    const float* __restrict__ biasA, const float* __restrict__ biasB,
    unsigned long long* __restrict__ hb64, uint32_t* __restrict__ xf,
    uint16_t* lds_x, uint16_t* lds_h, float* lds_p, float* lds_res)
{
    constexpr int DIL = 1 << LAYER;
    constexpr int SB = DIL;
    constexpr int T = S_ / DIL;
    constexpr int KIN = (LAYER == 0) ? FR : H_;
    constexpr int NJX = KIN / 64;
    constexpr int XTOT = SB * KIN;
    constexpr int XRS = (XTOT + 511) / 512;
    constexpr int KSH = (LAYER == 0) ? 7 : 9;
    constexpr int LOFF = (LAYER == 0) ? 0 : (LAYER - 1);
    constexpr bool WREG = (LAYER <= 1);      // Whh register residency
    constexpr bool EARLY = (SB <= 4);        // early h-poll issue
    constexpr bool XPROD = (LAYER == 0 || LAYER == 2);  // atomic x_out + flags
    constexpr bool XCONS = (LAYER == 1 || LAYER == 3);  // gated atomic x_in
    constexpr uint32_t TB = 1u;              // tag base (per-layer region)

    const int g = bid & 15, wgi = bid >> 4;
    const int tid = threadIdx.x;
    const int kg = tid >> 6;
    const int r6 = tid & 63;
    const int gp = r6 >> 5;
    const int um = r6 & 31;
    const int U0 = wgi * 32;
    const int row0 = (2 * gp) * H_ + U0 + um;
    const int row1 = row0 + H_;
    const int rl0 = (2 * gp) * 32 + um, rl1 = rl0 + 32;
    const int sb0 = g * SB;

    const uint4* WH = pwh + ((size_t)(LAYER * 64 + kg * 8)) * G4;

    uint4 h0c0, h1c0, h0c1, h1c1, h0c2, h1c2, h0c3, h1c3;
    uint4 h0c4, h1c4, h0c5, h1c5, h0c6, h1c6, h0c7, h1c7;
    if constexpr (WREG) {
        h0c0 = WH[(size_t)0 * G4 + row0]; h1c0 = WH[(size_t)0 * G4 + row1];
        h0c1 = WH[(size_t)1 * G4 + row0]; h1c1 = WH[(size_t)1 * G4 + row1];
        h0c2 = WH[(size_t)2 * G4 + row0]; h1c2 = WH[(size_t)2 * G4 + row1];
        h0c3 = WH[(size_t)3 * G4 + row0]; h1c3 = WH[(size_t)3 * G4 + row1];
        h0c4 = WH[(size_t)4 * G4 + row0]; h1c4 = WH[(size_t)4 * G4 + row1];
        h0c5 = WH[(size_t)5 * G4 + row0]; h1c5 = WH[(size_t)5 * G4 + row1];
        h0c6 = WH[(size_t)6 * G4 + row0]; h1c6 = WH[(size_t)6 * G4 + row1];
        h0c7 = WH[(size_t)7 * G4 + row0]; h1c7 = WH[(size_t)7 * G4 + row1];
    }

    const uint4* WI0;
    if constexpr (LAYER == 0) WI0 = pwi + ((size_t)(kg * NJX)) * G4;
    else                      WI0 = pwi + ((size_t)(LOFF * 64 + kg * 8)) * G4;

    const int b0 = tid >> 5, uu = tid & 31;
    const bool upd = tid < SB * 32;
    float biasv[4] = {0.f, 0.f, 0.f, 0.f};
    float cst = 0.0f;
    if (upd) {
        #pragma unroll
        for (int Gx = 0; Gx < 4; Gx++) {
            int RR = Gx * H_ + U0 + uu;
            if constexpr (LAYER == 0)
                biasv[Gx] = biasA[(size_t)(sb0 + b0) * G4 + RR];
            else
                biasv[Gx] = biasA[RR] + biasB[RR];
        }
    }
    const size_t pslot = (size_t)(sb0 + b0) * 256 + ((U0 + uu) >> 1);
    const int usb = sb0 + b0, ubg = usb >> LAYER, uk = usb & (DIL - 1);
    const int myprod = (tid & 511) >> 5;   // producer WG of this thread's units

    // ---- prologue ----
    if constexpr (XCONS) {   // gate token-0 prefetch: positions < DIL -> flag >= 2
        const uint32_t* fl = xf + (g * 16 + myprod) * 16;
        uint32_t fv = __hip_atomic_load(fl, __ATOMIC_RELAXED, SCOPE_AGENT);
        while (fv < 2u) {
            __builtin_amdgcn_s_sleep(1);
            fv = __hip_atomic_load(fl, __ATOMIC_RELAXED, SCOPE_AGENT);
        }
    }
    float xsr[XRS];
    #pragma unroll
    for (int rr = 0; rr < XRS; rr++) {
        int idx = tid + rr * 512;
        if (idx < XTOT) {
            int b = idx >> KSH, off = idx & (KIN - 1);
            int sb = sb0 + b, bg = sb >> LAYER, k = sb & (DIL - 1);
            const float* src = x_in + ((size_t)bg * S_ + k) * KIN + off;
            if constexpr (XCONS)
                xsr[rr] = __hip_atomic_load(src, __ATOMIC_RELAXED, SCOPE_AGENT);
            else
                xsr[rr] = *src;
        }
    }
    asm volatile("s_waitcnt vmcnt(0)" ::: "memory");
    __syncthreads();
    if (upd && ((uu & 1) == 0))
        __hip_atomic_store(hb64 + HV64 + pslot,
                           (unsigned long long)TB << 32,
                           __ATOMIC_RELAXED, SCOPE_AGENT);

    for (int t = 0; t < T; t++) {
        // ---- stage regs -> LDS (f16) + f32 residual slice ----
        #pragma unroll
        for (int rr = 0; rr < XRS; rr++) {
            int idx = tid + rr * 512;
            if (idx < XTOT) {
                int b = idx >> KSH, off = idx & (KIN - 1);
                lds_x[b * KIN + off] = f2h(xsr[rr]);
                if constexpr (LAYER > 0)
                    if ((off & ~31) == U0) lds_res[b * 32 + (off & 31)] = xsr[rr];
            }
        }
        __syncthreads();   // (a)

        // ---- residual -> register NOW (R15 race fix) ----
        float res = 0.f;
        if constexpr (LAYER > 0) {
            if (upd) res = lds_res[b0 * 32 + uu];
        }

        const unsigned long long* hrd = hb64 + (size_t)((t + 1) & 1) * HV64;
        const uint32_t want = TB + (uint32_t)t;

        // ---- early h-poll issue ----
        unsigned long long pve[EARLY ? SB : 1];
        if constexpr (EARLY) {
            if (tid < 256) {
                #pragma unroll
                for (int b = 0; b < SB; b++)
                    pve[b] = __hip_atomic_load(hrd + (size_t)(sb0 + b) * 256 + tid,
                                               __ATOMIC_RELAXED, SCOPE_AGENT);
            }
        }

        // ---- x-flag gate + token(t+1) prefetch ----
        if (t + 1 < T) {
            if constexpr (XCONS) {
                const uint32_t* fl = xf + (g * 16 + myprod) * 16;
                const uint32_t need = 2u * (uint32_t)(t + 2);
                uint32_t fv = __hip_atomic_load(fl, __ATOMIC_RELAXED, SCOPE_AGENT);
                while (fv < need) {
                    __builtin_amdgcn_s_sleep(1);
                    fv = __hip_atomic_load(fl, __ATOMIC_RELAXED, SCOPE_AGENT);
                }
            }
            #pragma unroll
            for (int rr = 0; rr < XRS; rr++) {
                int idx = tid + rr * 512;
                if (idx < XTOT) {
                    int b = idx >> KSH, off = idx & (KIN - 1);
                    int sb = sb0 + b, bg = sb >> LAYER, k = sb & (DIL - 1);
                    const float* src =
                        x_in + ((size_t)bg * S_ + (size_t)(t + 1) * DIL + k) * KIN + off;
                    if constexpr (XCONS)
                        xsr[rr] = __hip_atomic_load(src, __ATOMIC_RELAXED, SCOPE_AGENT);
                    else
                        xsr[rr] = *src;
                }
            }
        }

        // ---- x-part matvec ----
        float accA[SB], accB[SB];
        #pragma unroll
        for (int b = 0; b < SB; b++) { accA[b] = 0.f; accB[b] = 0.f; }
        if constexpr (LAYER >= 2) {
            #pragma unroll 4
            for (int j = 0; j < NJX; j++) XBODY(j)
        } else {
            #pragma unroll 2
            for (int j = 0; j < NJX; j++) XBODY(j)
        }

        // ---- drain prefetch/polls before spin (retries wait only on selves;
        //      also the in-place certificate: prefetch landed before publish) ----
        asm volatile("s_waitcnt vmcnt(0)" ::: "memory");

        // ---- h tag spin + h -> LDS ----
        if (tid < 256) {
            if constexpr (EARLY) {
                #pragma unroll
                for (int b = 0; b < SB; b++) {
                    unsigned long long v = pve[b];
                    while ((uint32_t)(v >> 32) != want) {
                        __builtin_amdgcn_s_sleep(1);
                        v = __hip_atomic_load(hrd + (size_t)(sb0 + b) * 256 + tid,
                                              __ATOMIC_RELAXED, SCOPE_AGENT);
                    }
                    ((uint32_t*)&lds_h[b * H_])[tid] = (uint32_t)v;
                }
            } else {
                unsigned long long pv[SB];
                #pragma unroll
                for (int b = 0; b < SB; b++)
                    pv[b] = __hip_atomic_load(hrd + (size_t)(sb0 + b) * 256 + tid,
                                              __ATOMIC_RELAXED, SCOPE_AGENT);
                #pragma unroll
                for (int b = 0; b < SB; b++) {
                    while ((uint32_t)(pv[b] >> 32) != want) {
                        __builtin_amdgcn_s_sleep(1);
                        pv[b] = __hip_atomic_load(hrd + (size_t)(sb0 + b) * 256 + tid,
                                                  __ATOMIC_RELAXED, SCOPE_AGENT);
                    }
                    ((uint32_t*)&lds_h[b * H_])[tid] = (uint32_t)pv[b];
                }
            }
        }
        __syncthreads();   // (b)

        // ---- recurrent matvec ----
        if constexpr (WREG) {
            HSTEP(0) HSTEP(1) HSTEP(2) HSTEP(3)
            HSTEP(4) HSTEP(5) HSTEP(6) HSTEP(7)
        } else {
            #pragma unroll 4
            for (int j = 0; j < 8; j++) {
                uint4 w0 = WH[(size_t)j * G4 + row0];
                uint4 w1 = WH[(size_t)j * G4 + row1];
                #pragma unroll
                for (int b = 0; b < SB; b++) {
                    uint4 hv = *(const uint4*)&lds_h[b * H_ + kg * 64 + j * 8];
                    accA[b] = dot8f(w0, hv, accA[b]);
                    accB[b] = dot8f(w1, hv, accB[b]);
                }
            }
        }

        // ---- partials; barrier (c) ----
        #pragma unroll
        for (int b = 0; b < SB; b++) {
            lds_p[(b * 8 + kg) * 132 + rl0] = accA[b];
            lds_p[(b * 8 + kg) * 132 + rl1] = accB[b];
        }
        asm volatile("s_waitcnt vmcnt(0)" ::: "memory");
        __syncthreads();   // (c)

        // ---- gates; tagged h publish; x_out; x-flag certify ----
        if (upd) {
            float gv[4];
            #pragma unroll
            for (int Gx = 0; Gx < 4; Gx++) {
                int rl = Gx * 32 + uu;
                float s = biasv[Gx];
                #pragma unroll
                for (int q = 0; q < 8; q++) s += lds_p[(b0 * 8 + q) * 132 + rl];
                gv[Gx] = s;
            }
            float ci = sigm(gv[0]), cf = sigm(gv[1]);
            float cg = tanhfast(gv[2]), co = sigm(gv[3]);
            cst = cf * cst + ci * cg;
            float hv = co * tanhfast(cst);
            uint32_t h16 = (uint32_t)f2h(hv);
            uint32_t partner = (uint32_t)__shfl_xor((int)h16, 1);
            if ((uu & 1) == 0)
                __hip_atomic_store(hb64 + (size_t)(t & 1) * HV64 + pslot,
                                   ((unsigned long long)(TB + (uint32_t)t + 1) << 32) |
                                   (unsigned long long)(h16 | (partner << 16)),
                                   __ATOMIC_RELAXED, SCOPE_AGENT);
            float* dst = x_out + ((size_t)ubg * S_ + (size_t)t * DIL + uk) * H_ + U0 + uu;
            if constexpr (XPROD)
                __hip_atomic_store(dst, hv + res, __ATOMIC_RELAXED, SCOPE_AGENT);
            else
                *dst = hv + res;
        }
        if constexpr (XPROD) {
            asm volatile("s_waitcnt vmcnt(0)" ::: "memory");
            if constexpr (SB >= 4) __syncthreads();   // L2: cross-wave upd stores
            if (tid == 0)
                __hip_atomic_store(xf + (g * 16 + wgi) * 16, (uint32_t)(t + 1),
                                   __ATOMIC_RELAXED, SCOPE_AGENT);
        }
    }
}

// ---------------------------------------------------------------------------
// Fused pair kernel. Mapping is PER-PAIR (R17 lesson):
//  - SEG=false (K1 = L0||L1): identity mapping. Round-robin dispatch puts
//    A_i and B_i on the SAME CU -> phase-interleaved A/B pairs (complementary
//    VALU/wait). Combined weight set 2.25MB < 4MB L2 -> no thrash (R16: K1
//    1.96ms this way; R17 segregated map put 2 lockstep same-layer WGs per
//    CU -> 2.9ms).
//  - SEG=true (K2 = L2||L3): XCD-segregated (A on XCDs 0-3, B on 4-7) so the
//    per-XCD weight working set is one 4MB layer slice (R16: mixed = 8MB ->
//    HBM thrash 6.3GB @2.47TB/s; R17 fix: FETCH -> 79MB).
// Mapping is perf-only: co-residency comes from strict 2-WG/CU capacity.
// ---------------------------------------------------------------------------
template <int LA, int LB, bool SEG>
__global__ __attribute__((amdgpu_waves_per_eu(4, 4))) __launch_bounds__(512)
void fused_scan(const float* xinA, float* xoutA,
                const float* xinB, float* xoutB,
                const uint4* __restrict__ pwiA, const uint4* __restrict__ pwiB,
                const uint4* __restrict__ pwh,
                const float* __restrict__ bA1, const float* __restrict__ bA2,
                const float* __restrict__ bB1, const float* __restrict__ bB2,
                unsigned long long* __restrict__ hb64, uint32_t* __restrict__ xf)
{
    constexpr int SBMX = 1 << LB;
    __shared__ __align__(16) uint16_t s_x[SBMX * 512];
    __shared__ __align__(16) uint16_t s_h[SBMX * 512];
    __shared__ float s_p[SBMX * 8 * 132];
    __shared__ float s_r[SBMX * 32];
    bool isA;
    int bid;
    if constexpr (SEG) {
        // XCD = blockIdx.x % 8. x<4 -> layer A on XCDs 0-3, else B on 4-7.
        // bid = wgi*16 + g, g = xe + 4*(q&3), wgi = q>>2 (bijective; a
        // group's 16 WGs share one XCD).
        const int x = (int)blockIdx.x & 7, q = (int)blockIdx.x >> 3;
        isA = (x < 4);
        const int xe = isA ? x : x - 4;
        bid = ((q >> 2) << 4) + (xe + 4 * (q & 3));
    } else {
        isA = (int)blockIdx.x < 256;
        bid = (int)blockIdx.x & 255;
    }
    if (isA)
        scan_body<LA>(bid, xinA, xoutA, pwiA, pwh, bA1, bA2,
                      hb64 + (size_t)LA * 2 * HV64, xf, s_x, s_h, s_p, s_r);
    else
        scan_body<LB>(bid, xinB, xoutB, pwiB, pwh, bB1, bB2,
                      hb64 + (size_t)LB * 2 * HV64, xf, s_x, s_h, s_p, s_r);
}

// ---------------------------------------------------------------------------
// out = x @ W_out.T + b_out   ([16384,512] x [512,128])
// ---------------------------------------------------------------------------
__global__ __launch_bounds__(256) void out_gemm(
    const float* __restrict__ x, const float* __restrict__ Wout,
    const float* __restrict__ bout, float* __restrict__ out)
{
    __shared__ __align__(16) float xs[8][H_];
    int tid = threadIdx.x;
    size_t tok0 = (size_t)blockIdx.x * 8;
    const float4* src = (const float4*)(x + tok0 * H_);
    for (int idx = tid; idx < 8 * H_ / 4; idx += 256)
        ((float4*)xs)[idx] = src[idx];
    __syncthreads();

    int col = tid & 127, th = tid >> 7;
    int tb = th * 4;
    float a0 = 0.f, a1 = 0.f, a2 = 0.f, a3 = 0.f;
    const float4* w = (const float4*)(Wout + (size_t)col * H_);
    #pragma unroll 4
    for (int j = 0; j < H_ / 4; j++) {
        float4 wv = w[j];
        float4 x0 = ((const float4*)xs[tb + 0])[j];
        float4 x1 = ((const float4*)xs[tb + 1])[j];
        float4 x2 = ((const float4*)xs[tb + 2])[j];
        float4 x3 = ((const float4*)xs[tb + 3])[j];
        a0 = fmaf(wv.x, x0.x, a0); a0 = fmaf(wv.y, x0.y, a0); a0 = fmaf(wv.z, x0.z, a0); a0 = fmaf(wv.w, x0.w, a0);
        a1 = fmaf(wv.x, x1.x, a1); a1 = fmaf(wv.y, x1.y, a1); a1 = fmaf(wv.z, x1.z, a1); a1 = fmaf(wv.w, x1.w, a1);
        a2 = fmaf(wv.x, x2.x, a2); a2 = fmaf(wv.y, x2.y, a2); a2 = fmaf(wv.z, x2.z, a2); a2 = fmaf(wv.w, x2.w, a2);
        a3 = fmaf(wv.x, x3.x, a3); a3 = fmaf(wv.y, x3.y, a3); a3 = fmaf(wv.z, x3.z, a3); a3 = fmaf(wv.w, x3.w, a3);
    }
    float bo = bout[col];
    out[(tok0 + tb + 0) * FR + col] = a0 + bo;
    out[(tok0 + tb + 1) * FR + col] = a1 + bo;
    out[(tok0 + tb + 2) * FR + col] = a2 + bo;
    out[(tok0 + tb + 3) * FR + col] = a3 + bo;
}

// ---------------------------------------------------------------------------
extern "C" void kernel_launch(void* const* d_in, const int* in_sizes, int n_in,
                              void* d_out, int out_size, void* d_ws, size_t ws_size,
                              hipStream_t stream)
{
    const float* inputs = (const float*)d_in[0];
    const float* moods  = (const float*)d_in[1];
    const float* W_mood = (const float*)d_in[2];
    const float* b_mood = (const float*)d_in[3];
    const float* W_ih0  = (const float*)d_in[4];
    const float* W_hh0  = (const float*)d_in[5];
    const float* b_ih0  = (const float*)d_in[6];
    const float* b_hh0  = (const float*)d_in[7];
    const float* W_ih_r = (const float*)d_in[8];
    const float* W_hh_r = (const float*)d_in[9];
    const float* b_ih_r = (const float*)d_in[10];
    const float* b_hh_r = (const float*)d_in[11];
    const float* W_out  = (const float*)d_in[12];
    const float* b_out  = (const float*)d_in[13];

    float* ws = (float*)d_ws;
    float* mc = ws;                                    // 32768 floats
    float* xA = ws + 32768;                            // 8388608 floats (in-place x)
    unsigned long long* hb64 = (unsigned long long*)(xA + 8388608);  // 4 layers x 2*HV64 = 2MB
    uint32_t* xf0 = (uint32_t*)(hb64 + 8 * HV64);      // 16KB (L0->L1 flags)
    uint32_t* xf2 = xf0 + NXF;                         // 16KB (L2->L3 flags)
    uint4* pwh  = (uint4*)(xf2 + NXF);                 // 524288 uint4
    uint4* pwi0 = pwh + NCH_WHH;                       // 32768 uint4
    uint4* pwir = pwi0 + NCH_WI0;                      // 393216 uint4
    // total ~51 MB

    // zero all tags + flags each launch (replay-safe)
    (void)hipMemsetAsync(hb64, 0, 8 * HV64 * sizeof(unsigned long long)
                                  + 2 * NXF * sizeof(uint32_t), stream);
    mood_kernel<<<16, 256, 0, stream>>>(moods, W_mood, b_mood, W_ih0, b_ih0, b_hh0, mc);
    pack_kernel<<<(NCH_TOT + 255) / 256, 256, 0, stream>>>(
        W_hh0, W_hh_r, W_ih0, W_ih_r, pwh, pwi0, pwir);

    // K1: L0 || L1, identity mapping (A/B phase-interleave per CU)
    fused_scan<0, 1, false><<<512, 512, 0, stream>>>(
        inputs, xA, xA, xA, pwi0, pwir, pwh,
        mc, nullptr, b_ih_r, b_hh_r, hb64, xf0);
    // K2: L2 || L3, XCD-segregated mapping (weight-set fits L2 per XCD)
    fused_scan<2, 3, true><<<512, 512, 0, stream>>>(
        xA, xA, xA, xA, pwir, pwir, pwh,
        b_ih_r + G4, b_hh_r + G4, b_ih_r + 2 * G4, b_hh_r + 2 * G4, hb64, xf2);

    out_gemm<<<2048, 256, 0, stream>>>(xA, W_out, b_out, (float*)d_out);
}